// Round 19
// baseline (242.834 us; speedup 1.0000x reference)
//
#include <hip/hip_runtime.h>

#define H_N 28
#define KVH_N 4
#define D_N 128
#define S_N 2048
#define E_N 3584
#define NQKV 4608

typedef unsigned short u16;
typedef unsigned int u32;
typedef __bf16 bf16x8 __attribute__((ext_vector_type(8)));
typedef float f32x4 __attribute__((ext_vector_type(4)));
typedef float f32x16 __attribute__((ext_vector_type(16)));
typedef unsigned short u16x4 __attribute__((ext_vector_type(4)));
typedef unsigned short u16x8 __attribute__((ext_vector_type(8)));
typedef unsigned int u32x2 __attribute__((ext_vector_type(2)));
typedef unsigned int u32x4 __attribute__((ext_vector_type(4)));

typedef __attribute__((address_space(1))) void gvoid_t;
typedef __attribute__((address_space(3))) void lvoid_t;

static __device__ __forceinline__ u16 f2bf(float f) {
  __bf16 h = (__bf16)f;
  return __builtin_bit_cast(unsigned short, h);
}

static __device__ __forceinline__ float bf2f(u16 b) {
  u32 u = (u32)b << 16;
  return __builtin_bit_cast(float, u);
}

static __device__ __forceinline__ void gload16(const void* g, void* l) {
  __builtin_amdgcn_global_load_lds((gvoid_t*)g, (lvoid_t*)l, 16, 0, 0);
}

static __device__ __forceinline__ void gload4(const void* g, void* l) {
  __builtin_amdgcn_global_load_lds((gvoid_t*)g, (lvoid_t*)l, 4, 0, 0);
}

static __device__ __forceinline__ u32 cvt_pk_bf16(float lo, float hi) {
  u32 r;
  asm("v_cvt_pk_bf16_f32 %0, %1, %2" : "=v"(r) : "v"(lo), "v"(hi));
  return r;
}

static __device__ __forceinline__ void pl32swap(u32& a, u32& b) {
  asm volatile("v_permlane32_swap_b32 %0, %1" : "+v"(a), "+v"(b));
}

static __device__ __forceinline__ float vmax16(f32x16 v) {
  float a = fmaxf(fmaxf(v[0], v[1]), fmaxf(v[2], v[3]));
  float b = fmaxf(fmaxf(v[4], v[5]), fmaxf(v[6], v[7]));
  float c = fmaxf(fmaxf(v[8], v[9]), fmaxf(v[10], v[11]));
  float d = fmaxf(fmaxf(v[12], v[13]), fmaxf(v[14], v[15]));
  return fmaxf(fmaxf(a, b), fmaxf(c, d));
}

static __device__ __forceinline__ float vsum16(f32x16 v) {
  float a = (v[0] + v[1]) + (v[2] + v[3]);
  float b = (v[4] + v[5]) + (v[6] + v[7]);
  float c = (v[8] + v[9]) + (v[10] + v[11]);
  float d = (v[12] + v[13]) + (v[14] + v[15]);
  return (a + b) + (c + d);
}

// -------- merged prepass: qw/kw/vw/ow transposes + hs f32->bf16, one launch ----------
__global__ __launch_bounds__(256) void k_wtrans(const float* __restrict__ qw,
                                                const float* __restrict__ kw,
                                                const float* __restrict__ vw,
                                                const float* __restrict__ ow,
                                                const float* __restrict__ hs,
                                                u16* __restrict__ wt,
                                                u16* __restrict__ wt2,
                                                u16* __restrict__ hsb) {
  int bx = blockIdx.x;
  if (bx >= 128) {
    int g = ((bx - 128) * 56 + blockIdx.y) * 256 + threadIdx.x;  // 8-elem groups
    int row = g / 448, c8 = g % 448;
    const float4* p = (const float4*)(hs + (size_t)g * 8);
    float4 a = p[0], b = p[1];
    u16x8 r;
    r[0] = f2bf(a.x); r[1] = f2bf(a.y); r[2] = f2bf(a.z); r[3] = f2bf(a.w);
    r[4] = f2bf(b.x); r[5] = f2bf(b.y); r[6] = f2bf(b.z); r[7] = f2bf(b.w);
    int dc8 = c8 ^ (row & 7);
    *(u16x8*)(hsb + (size_t)row * E_N + dc8 * 8) = r;
    return;
  }
  __shared__ float t[64][65];
  const float* in;
  u16* out;
  int C, c0;
  if (bx < 56) {
    in = qw; out = wt; C = 3584; c0 = bx * 64;
  } else if (bx < 64) {
    in = kw; out = wt + (size_t)3584 * 3584; C = 512; c0 = (bx - 56) * 64;
  } else if (bx < 72) {
    in = vw; out = wt + (size_t)4096 * 3584; C = 512; c0 = (bx - 64) * 64;
  } else {
    in = ow; out = wt2; C = 3584; c0 = (bx - 72) * 64;
  }
  int r0 = blockIdx.y * 64;
  int lr = threadIdx.x >> 6, lc = threadIdx.x & 63;
#pragma unroll
  for (int i = 0; i < 64; i += 4)
    t[lr + i][lc] = in[(size_t)(r0 + lr + i) * C + c0 + lc];
  __syncthreads();
#pragma unroll
  for (int i = 0; i < 64; i += 4) {
    int orow = c0 + lr + i;
    int sw = (orow & 7) << 3;
    out[(size_t)orow * 3584 + r0 + (lc ^ sw)] = f2bf(t[lc][lr + i]);
  }
}

// =================== GEMM BMx256, BK=64, 8 waves, 2-phase counted-vmcnt ================
// 2 phases/tile (barriers 8->4 vs prior 4-phase; 1 block/CU so barrier drain is fully
// exposed — halving count is the lever):
//  P0: {rdA-all + rdB q01; stage (T+1).B2,B3 -> buf^1; BARR; LGKM0; MFMA q01; BARR}
//  P1: {rdB q23; stage (T+2).{B0,B1,A*} -> cur; vmcnt(ISS-2); BARR; LGKM0; MFMA q23; BARR}
// FIFO: T+1 issues = 6 (T-1 P1) + 2 (T P0) = ISS; at T's P1 wait outstanding =
// ISS + (ISS-2) -> vmcnt(ISS-2) drains exactly tile T+1. Slot overwrites all occur
// >= 1 barrier after that slot's last read (drained by the preceding LGKM0).
// EPI=1: fused QKV epilogue — Q (bias); K (bias+RoPE+(s&15)<<3 swizzle, final);
// V (bias, transposed + within-64 swizzle).
#define BARR __builtin_amdgcn_s_barrier()
#define LGKM0 asm volatile("s_waitcnt lgkmcnt(0)" ::: "memory")
#define VMW0 asm volatile("s_waitcnt vmcnt(0)" ::: "memory")

template <int BM, int EPI>
__global__ __launch_bounds__(512, 2) void k_gemm(const u16* __restrict__ A,
                                                 const u16* __restrict__ Bt,
                                                 float* __restrict__ Cout,
                                                 int Nn, int nxt,
                                                 const float* __restrict__ qb,
                                                 const float* __restrict__ kb,
                                                 const float* __restrict__ vb,
                                                 const float* __restrict__ cosb,
                                                 const float* __restrict__ sinb,
                                                 u16* __restrict__ Qo,
                                                 u16* __restrict__ Ko,
                                                 u16* __restrict__ Vo) {
  constexpr int NA64 = BM / 64;                 // full 64-row A units
  constexpr bool HAS_A2 = (BM % 64) != 0;       // 32-row tail
  constexpr int NFR = BM / 32;                  // m-frags per wave
  constexpr int ISS = NA64 + (HAS_A2 ? 2 : 0) + 4;  // vmem issues per tile
  constexpr int LROWS = BM + 256;
  __shared__ __align__(16) u16 L[2 * LROWS * 64];
  const int K = 3584, NKT = 56;
  const int tid = threadIdx.x;
  const int lane = tid & 63;
  const int w = tid >> 6;
  const int lr = lane & 15, lh = lane >> 4, lh8 = lh * 8;
  const int swz = (lr & 7) << 3;
  const int wr = w >> 2, wc = w & 3;  // 2 M-waves x 4 N-waves

  // bijective XCD swizzle (m204)
  const int nwg = gridDim.x;
  const int bid = blockIdx.x;
  const int q8 = nwg >> 3, r8 = nwg & 7;
  const int xcd = bid & 7, idx = bid >> 3;
  const int lb = (xcd < r8 ? xcd * (q8 + 1) : r8 * (q8 + 1) + (xcd - r8) * q8) + idx;
  const size_t m0 = (size_t)(lb / nxt) * BM;
  const size_t n0 = (size_t)(lb % nxt) << 8;

  const u16* __restrict__ Ab = A + m0 * K;
  const u16* __restrict__ Bb = Bt + n0 * K;

  const int srow = tid >> 3, scol8 = tid & 7;
  auto stg = [&](int buf, int u, int kt) {  // 64-row units: u<NA64 A, else B
    if (kt >= NKT) return;
    const u16* src;
    int ldsrow;
    if (u < NA64) {
      src = Ab + (size_t)(u * 64 + srow) * K;
      ldsrow = u * 64 + srow;
    } else {
      src = Bb + (size_t)((u - NA64) * 64 + srow) * K;
      ldsrow = BM + (u - NA64) * 64 + srow;
    }
    gload16(src + kt * 64 + scol8 * 8, &L[buf * (LROWS * 64) + ldsrow * 64 + scol8 * 8]);
  };
  auto stgA2 = [&](int buf, int kt) {  // 32-row tail, 2 width-4 issues (all waves)
    if constexpr (HAS_A2) {
      if (kt >= NKT) return;
      int c2 = (tid & 31) * 2;
#pragma unroll
      for (int jj = 0; jj < 2; ++jj) {
        int rr = NA64 * 64 + jj * 16 + (tid >> 5);
        gload4(Ab + (size_t)rr * K + kt * 64 + c2,
               &L[buf * (LROWS * 64) + rr * 64 + c2]);
      }
    }
  };
  auto vmw = [&]() {
    if constexpr (ISS == 8) { asm volatile("s_waitcnt vmcnt(6)" ::: "memory"); }
    else if constexpr (ISS == 7) { asm volatile("s_waitcnt vmcnt(5)" ::: "memory"); }
    else { asm volatile("s_waitcnt vmcnt(4)" ::: "memory"); }
  };

  f32x4 acc[NFR][4];
#pragma unroll
  for (int i = 0; i < NFR; i++)
#pragma unroll
    for (int j = 0; j < 4; j++) acc[i][j] = f32x4{0.f, 0.f, 0.f, 0.f};

  bf16x8 afAll[NFR][2], bq[2][2];

  auto rdAall = [&](int LB) {
#pragma unroll
    for (int mm = 0; mm < NFR; ++mm)
#pragma unroll
      for (int kk = 0; kk < 2; ++kk)
        afAll[mm][kk] = *(const bf16x8*)&L[LB + (wr * (BM / 2) + mm * 16 + lr) * 64 +
                                           ((kk * 32 + lh8) ^ swz)];
  };
  auto rdB = [&](int LB, int qbase) {
#pragma unroll
    for (int j = 0; j < 2; ++j)
#pragma unroll
      for (int kk = 0; kk < 2; ++kk)
        bq[j][kk] = *(const bf16x8*)&L[LB + (BM + (qbase + j) * 64 + wc * 16 + lr) * 64 +
                                       ((kk * 32 + lh8) ^ swz)];
  };
  auto mmAll = [&](int qbase) {
    __builtin_amdgcn_s_setprio(1);
#pragma unroll
    for (int mm = 0; mm < NFR; ++mm)
#pragma unroll
      for (int j = 0; j < 2; ++j)
#pragma unroll
        for (int kk = 0; kk < 2; ++kk)
          acc[mm][qbase + j] = __builtin_amdgcn_mfma_f32_16x16x32_bf16(
              afAll[mm][kk], bq[j][kk], acc[mm][qbase + j], 0, 0, 0);
    __builtin_amdgcn_s_setprio(0);
  };

  // prologue: tile0 all units; tile1 {B0,B1,A*}; counted wait drains tile0.
#pragma unroll
  for (int u = 0; u < NA64 + 4; ++u) stg(0, u, 0);
  stgA2(0, 0);
  stg(1, NA64 + 0, 1); stg(1, NA64 + 1, 1);
#pragma unroll
  for (int u = 0; u < NA64; ++u) stg(1, u, 1);
  stgA2(1, 1);
  vmw();
  BARR;

  for (int T = 0; T < NKT; ++T) {
    const int cur = T & 1;
    const int LB = cur * (LROWS * 64);
    // ---- P0: rdA-all + rdB q01; stage (T+1).B2,B3 -> buf^1 ----
    rdAall(LB);
    rdB(LB, 0);
    stg(cur ^ 1, NA64 + 2, T + 1);
    stg(cur ^ 1, NA64 + 3, T + 1);
    BARR; LGKM0;
    mmAll(0);
    BARR;
    // ---- P1: rdB q23; stage (T+2).{B0,B1,A*} -> cur; counted wait ----
    rdB(LB, 2);
    stg(cur, NA64 + 0, T + 2);
    stg(cur, NA64 + 1, T + 2);
#pragma unroll
    for (int u = 0; u < NA64; ++u) stg(cur, u, T + 2);
    stgA2(cur, T + 2);
    if (T + 2 < NKT) { vmw(); } else { VMW0; }
    BARR; LGKM0;
    mmAll(2);
    BARR;
  }

  if constexpr (EPI == 0) {
    const size_t Nsz = (size_t)Nn;
#pragma unroll
    for (int m = 0; m < NFR; ++m) {
      size_t row = m0 + wr * (BM / 2) + m * 16 + lh * 4;
      if (row < 2048) {
#pragma unroll
        for (int p = 0; p < 4; ++p) {
          size_t col = n0 + p * 64 + wc * 16 + lr;
#pragma unroll
          for (int r = 0; r < 4; ++r) Cout[(row + r) * Nsz + col] = acc[m][p][r];
        }
      }
    }
  } else {
    const int ntile = (int)(n0 >> 8);  // 0..17
#pragma unroll
    for (int m = 0; m < NFR; ++m) {
      size_t row = m0 + wr * (BM / 2) + m * 16 + lh * 4;
      if (row >= 2048) continue;
      if (ntile < 14) {  // Q (bias only, unroped — attn ropes in-register)
#pragma unroll
        for (int p = 0; p < 4; ++p) {
          int col = (int)n0 + p * 64 + wc * 16 + lr;
          int hh = col >> 7, d = col & 127;
          float bias = qb[col];
#pragma unroll
          for (int r = 0; r < 4; ++r)
            Qo[((size_t)hh * S_N + row + r) * D_N + d] = f2bf(acc[m][p][r] + bias);
        }
      } else if (ntile < 16) {
        // K: bias + RoPE + swizzled write (FINAL). Pair (p=2pp, p=2pp+1) = (d0, d0+64)
        // of kvh = (ntile-14)*2 + pp; d0 = wc*16+lr in [0,64).
        int d0 = wc * 16 + lr;
#pragma unroll
        for (int pp = 0; pp < 2; ++pp) {
          int kvh = (ntile - 14) * 2 + pp;
          float blo = kb[kvh * 128 + d0];
          float bhi = kb[kvh * 128 + d0 + 64];
#pragma unroll
          for (int r = 0; r < 4; ++r) {
            int s = (int)row + r;
            float cl = cosb[s * D_N + d0], sl = sinb[s * D_N + d0];
            float ch = cosb[s * D_N + d0 + 64], sh = sinb[s * D_N + d0 + 64];
            float x0 = acc[m][2 * pp][r] + blo;
            float x1 = acc[m][2 * pp + 1][r] + bhi;
            float y0 = x0 * cl - x1 * sl;
            float y1 = x1 * ch + x0 * sh;
            int sw = (s & 15) << 3;
            u16* kp = Ko + ((size_t)kvh * S_N + s) * D_N;
            kp[d0 ^ sw] = f2bf(y0);
            kp[(d0 + 64) ^ sw] = f2bf(y1);
          }
        }
      } else {  // V -> transposed [cc][s], within-64 swizzle; 4-run contiguous in s
#pragma unroll
        for (int p = 0; p < 4; ++p) {
          int col = (int)n0 + p * 64 + wc * 16 + lr;
          int cc = col - 4096;
          float bias = vb[cc];
          int s = (int)row;
          int pos = (s & ~63) | ((s & 63) ^ ((cc & 7) << 3));
          u16x4 vv;
#pragma unroll
          for (int r = 0; r < 4; ++r) vv[r] = f2bf(acc[m][p][r] + bias);
          *(u16x4*)(Vo + (size_t)cc * S_N + pos) = vv;
        }
      }
    }
  }
}

// ---------------- flash attention, GQA, causal; Q-RoPE fused in prologue ----------------
// qt map: constant-sum pairing — under round-robin bid->CU, CU k hosts bids k and
// k+256; qt(h<16)=15-bx, qt(h>=16)=bx => per-CU step sum == 15 (balanced makespan).
#define SB0 __builtin_amdgcn_sched_barrier(0)

__global__ __launch_bounds__(256, 2) void k_attn(const u16* __restrict__ Q,
                                                 const u16* __restrict__ Kc,
                                                 const u16* __restrict__ Vt,
                                                 const float* __restrict__ cosb,
                                                 const float* __restrict__ sinb,
                                                 u16* __restrict__ Aout) {
  __shared__ __align__(16) u16 Klds[2][64 * 128];
  __shared__ __align__(16) u16 Vlds[2][128 * 64];
  const int h = blockIdx.y;
  const int kvh = h / 7;  // H/KVH = 7
  const int qt = (blockIdx.y & 16) ? (blockIdx.x & 15) : ((15 - blockIdx.x) & 15);
  const int q0 = qt * 128;
  const int tid = threadIdx.x, w = tid >> 6, lane = tid & 63;
  const int l31 = lane & 31, hi = lane >> 5;
  const int hi8 = hi * 8;
  const int swK = (l31 & 15) << 3;  // K-read swizzle
  const int swV = (l31 & 7) << 3;   // V-read swizzle
  const int qloc = w * 32 + l31;
  const int qrow = q0 + qloc;

  // Q fragments with in-register RoPE: frag f (d<64) pairs with f+4 (d+64).
  bf16x8 qf[8];
  {
    const u16* qp = Q + ((size_t)h * S_N + qrow) * D_N + hi8;
    const float* cb = cosb + (size_t)qrow * D_N + hi8;
    const float* sb = sinb + (size_t)qrow * D_N + hi8;
#pragma unroll
    for (int f = 0; f < 4; ++f) {
      u16x8 ulo = __builtin_bit_cast(u16x8, *(const bf16x8*)(qp + f * 16));
      u16x8 uhi = __builtin_bit_cast(u16x8, *(const bf16x8*)(qp + (f + 4) * 16));
      u16x8 olo, ohi;
#pragma unroll
      for (int e = 0; e < 8; ++e) {
        float xl = bf2f(ulo[e]), xh = bf2f(uhi[e]);
        float cl = cb[f * 16 + e], sl = sb[f * 16 + e];
        float ch = cb[(f + 4) * 16 + e], sh = sb[(f + 4) * 16 + e];
        olo[e] = f2bf(xl * cl - xh * sl);
        ohi[e] = f2bf(xh * ch + xl * sh);
      }
      qf[f] = __builtin_bit_cast(bf16x8, olo);
      qf[f + 4] = __builtin_bit_cast(bf16x8, ohi);
    }
  }

  f32x16 o[4];
#pragma unroll
  for (int i = 0; i < 4; i++)
#pragma unroll
    for (int r = 0; r < 16; r++) o[i][r] = 0.f;

  float m2 = -3.0e38f;
  float lsum = 0.f;
  const float msc = 0.12751743f;  // 1/sqrt(128) * log2(e)

  auto stageKV = [&](int buf, int t) {
    const u16* ks = Kc + ((size_t)kvh * S_N + t * 64) * D_N;
#pragma unroll
    for (int j = 0; j < 4; ++j)
      gload16(ks + (j * 256 + tid) * 8, &Klds[buf][(j * 256 + tid) * 8]);
    const u16* vs = Vt + (size_t)kvh * D_N * S_N + t * 64;
#pragma unroll
    for (int j = 0; j < 4; ++j) {
      int idx = j * 256 + tid;
      int dd = idx >> 3, cw = idx & 7;
      gload16(vs + (size_t)dd * S_N + cw * 8, &Vlds[buf][idx * 8]);
    }
  };

  const int nt = 2 * qt + 2;
  stageKV(0, 0);
  for (int t = 0; t < nt; ++t) {
    const int cur = t & 1;
    if (t + 1 < nt) {
      stageKV(cur ^ 1, t + 1);
      asm volatile("s_waitcnt vmcnt(8)" ::: "memory");  // tile t resident (FIFO)
    } else {
      asm volatile("s_waitcnt vmcnt(0)" ::: "memory");
    }
    SB0; BARR; SB0;
    f32x16 sacc[2];
#pragma unroll
    for (int i = 0; i < 2; i++)
#pragma unroll
      for (int r = 0; r < 16; r++) sacc[i][r] = 0.f;
    __builtin_amdgcn_s_setprio(1);
#pragma unroll
    for (int dstep = 0; dstep < 8; ++dstep)
#pragma unroll
      for (int ksub = 0; ksub < 2; ++ksub) {
        bf16x8 ka =
            *(const bf16x8*)&Klds[cur][(ksub * 32 + l31) * D_N + ((dstep * 16 + hi8) ^ swK)];
        sacc[ksub] = __builtin_amdgcn_mfma_f32_32x32x16_bf16(ka, qf[dstep], sacc[ksub], 0, 0, 0);
      }
    __builtin_amdgcn_s_setprio(0);
    if (t >= nt - 2) {
#pragma unroll
      for (int ksub = 0; ksub < 2; ++ksub)
#pragma unroll
        for (int r = 0; r < 16; ++r) {
          int kvg = t * 64 + ksub * 32 + (r & 3) + 8 * (r >> 2) + 4 * hi;
          sacc[ksub][r] = (kvg <= qrow) ? sacc[ksub][r] * msc : -3.0e38f;
        }
    } else {
#pragma unroll
      for (int ksub = 0; ksub < 2; ++ksub)
#pragma unroll
        for (int r = 0; r < 16; ++r) sacc[ksub][r] *= msc;
    }
    float tmax = fmaxf(vmax16(sacc[0]), vmax16(sacc[1]));
    tmax = fmaxf(tmax, __shfl_xor(tmax, 32));  // cross-half max
    if (__any(tmax > m2 + 8.0f)) {
      float m2new = fmaxf(m2, tmax);
      float scl = __builtin_amdgcn_exp2f(m2 - m2new);
#pragma unroll
      for (int i = 0; i < 4; i++)
#pragma unroll
        for (int r = 0; r < 16; r++) o[i][r] *= scl;
      lsum *= scl;
      m2 = m2new;
    }
#pragma unroll
    for (int ksub = 0; ksub < 2; ++ksub) {
#pragma unroll
      for (int r = 0; r < 16; ++r)
        sacc[ksub][r] = __builtin_amdgcn_exp2f(sacc[ksub][r] - m2);
      lsum += vsum16(sacc[ksub]);
    }
    __builtin_amdgcn_s_setprio(1);
#pragma unroll
    for (int ksub = 0; ksub < 2; ++ksub) {
      u32 pw[8];
#pragma unroll
      for (int i = 0; i < 8; ++i) pw[i] = cvt_pk_bf16(sacc[ksub][2 * i], sacc[ksub][2 * i + 1]);
      pl32swap(pw[0], pw[2]);
      pl32swap(pw[1], pw[3]);
      pl32swap(pw[4], pw[6]);
      pl32swap(pw[5], pw[7]);
#pragma unroll
      for (int j = 0; j < 2; ++j) {
        u32x4 fw = {pw[j * 4 + 0], pw[j * 4 + 1], pw[j * 4 + 2], pw[j * 4 + 3]};
        bf16x8 pb = __builtin_bit_cast(bf16x8, fw);
#pragma unroll
        for (int dsub = 0; dsub < 4; ++dsub) {
          bf16x8 va = *(const bf16x8*)&Vlds[cur][(dsub * 32 + l31) * 64 +
                                                 ((ksub * 32 + j * 16 + hi8) ^ swV)];
          o[dsub] = __builtin_amdgcn_mfma_f32_32x32x16_bf16(va, pb, o[dsub], 0, 0, 0);
        }
      }
    }
    __builtin_amdgcn_s_setprio(0);
    SB0; BARR; SB0;
  }
  float lt = lsum + __shfl_xor(lsum, 32);
  float ri = 1.0f / lt;
  u16* op = Aout + (size_t)qrow * E_N + h * D_N;
  const int sw2 = (qrow & 7) << 3;  // GEMM-A pre-swizzle
#pragma unroll
  for (int dsub = 0; dsub < 4; ++dsub)
#pragma unroll
    for (int g = 0; g < 4; ++g) {
      int dbase = dsub * 32 + 8 * g + 4 * hi;
      u32x2 wv;
      wv[0] = (u32)f2bf(o[dsub][g * 4 + 0] * ri) | ((u32)f2bf(o[dsub][g * 4 + 1] * ri) << 16);
      wv[1] = (u32)f2bf(o[dsub][g * 4 + 2] * ri) | ((u32)f2bf(o[dsub][g * 4 + 3] * ri) << 16);
      *(u32x2*)(op + (dbase ^ sw2)) = wv;
    }
}

extern "C" void kernel_launch(void* const* d_in, const int* in_sizes, int n_in,
                              void* d_out, int out_size, void* d_ws, size_t ws_size,
                              hipStream_t stream) {
  const float* hs   = (const float*)d_in[0];
  const float* cosb = (const float*)d_in[1];
  const float* sinb = (const float*)d_in[2];
  // d_in[3] = attn_mask (causal tril — applied analytically)
  const float* qw = (const float*)d_in[4];
  const float* qb = (const float*)d_in[5];
  const float* kw = (const float*)d_in[6];
  const float* kb = (const float*)d_in[7];
  const float* vw = (const float*)d_in[8];
  const float* vb = (const float*)d_in[9];
  const float* ow = (const float*)d_in[10];
  float* outp = (float*)d_out;

  char* ws = (char*)d_ws;
  u16* hsb    = (u16*)(ws);                       // 2048x3584 bf16 (swz)           14.7MB
  u16* wt     = (u16*)(ws + 14680064);            // 4608x3584 bf16 (swz)             33MB
  u16* wt2    = (u16*)(ws + 47710208);            // 3584x3584 ow^T bf16 (swz)      25.7MB
  u16* attn_o = (u16*)(ws + 73400320);            // 2048x3584 bf16 (swz)           14.7MB
  u16* Qb     = (u16*)(ws + 88080384);            // [28][2048][128] (unroped)      14.7MB
  u16* Kb     = (u16*)(ws + 102760448);           // [4][2048][128] (roped+swz)       2MB
  u16* Vtb    = (u16*)(ws + 104857600);           // [512][2048] (swz within-64)      2MB

  // 1. merged prepass: weight transposes + hs->bf16 (one launch)
  k_wtrans<<<dim3(192, 56), dim3(256), 0, stream>>>(qw, kw, vw, ow, hs, wt, wt2, hsb);
  // 2. QKV GEMM, BM=160 (234 blocks, 91% fill), fused bias+RoPE(K)+layout epilogue
  k_gemm<160, 1><<<dim3(234), dim3(512), 0, stream>>>(hsb, wt, nullptr, 4608, 18,
                                                      qb, kb, vb, cosb, sinb, Qb, Kb, Vtb);
  // 3. attention -> attn_o (bf16, GEMM-swizzled); Q roped in-register
  k_attn<<<dim3(16, 28), dim3(256), 0, stream>>>(Qb, Kb, Vtb, cosb, sinb, attn_o);
  // 4. output projection, BM=128 (224 blocks)
  k_gemm<128, 0><<<dim3(224), dim3(512), 0, stream>>>(attn_o, wt2, outp, 3584, 14,
                                                      nullptr, nullptr, nullptr,
                                                      nullptr, nullptr,
                                                      nullptr, nullptr, nullptr);
}

// Round 20
// 237.407 us; speedup vs baseline: 1.0229x; 1.0229x over previous
//
#include <hip/hip_runtime.h>

#define H_N 28
#define KVH_N 4
#define D_N 128
#define S_N 2048
#define E_N 3584
#define NQKV 4608

typedef unsigned short u16;
typedef unsigned int u32;
typedef __bf16 bf16x8 __attribute__((ext_vector_type(8)));
typedef float f32x4 __attribute__((ext_vector_type(4)));
typedef float f32x16 __attribute__((ext_vector_type(16)));
typedef unsigned short u16x4 __attribute__((ext_vector_type(4)));
typedef unsigned short u16x8 __attribute__((ext_vector_type(8)));
typedef unsigned int u32x2 __attribute__((ext_vector_type(2)));
typedef unsigned int u32x4 __attribute__((ext_vector_type(4)));

typedef __attribute__((address_space(1))) void gvoid_t;
typedef __attribute__((address_space(3))) void lvoid_t;

static __device__ __forceinline__ u16 f2bf(float f) {
  __bf16 h = (__bf16)f;
  return __builtin_bit_cast(unsigned short, h);
}

static __device__ __forceinline__ float bf2f(u16 b) {
  u32 u = (u32)b << 16;
  return __builtin_bit_cast(float, u);
}

static __device__ __forceinline__ void gload16(const void* g, void* l) {
  __builtin_amdgcn_global_load_lds((gvoid_t*)g, (lvoid_t*)l, 16, 0, 0);
}

static __device__ __forceinline__ void gload4(const void* g, void* l) {
  __builtin_amdgcn_global_load_lds((gvoid_t*)g, (lvoid_t*)l, 4, 0, 0);
}

static __device__ __forceinline__ u32 cvt_pk_bf16(float lo, float hi) {
  u32 r;
  asm("v_cvt_pk_bf16_f32 %0, %1, %2" : "=v"(r) : "v"(lo), "v"(hi));
  return r;
}

static __device__ __forceinline__ void pl32swap(u32& a, u32& b) {
  asm volatile("v_permlane32_swap_b32 %0, %1" : "+v"(a), "+v"(b));
}

static __device__ __forceinline__ float vmax16(f32x16 v) {
  float a = fmaxf(fmaxf(v[0], v[1]), fmaxf(v[2], v[3]));
  float b = fmaxf(fmaxf(v[4], v[5]), fmaxf(v[6], v[7]));
  float c = fmaxf(fmaxf(v[8], v[9]), fmaxf(v[10], v[11]));
  float d = fmaxf(fmaxf(v[12], v[13]), fmaxf(v[14], v[15]));
  return fmaxf(fmaxf(a, b), fmaxf(c, d));
}

static __device__ __forceinline__ float vsum16(f32x16 v) {
  float a = (v[0] + v[1]) + (v[2] + v[3]);
  float b = (v[4] + v[5]) + (v[6] + v[7]);
  float c = (v[8] + v[9]) + (v[10] + v[11]);
  float d = (v[12] + v[13]) + (v[14] + v[15]);
  return (a + b) + (c + d);
}

// -------- merged prepass: qw/kw/vw/ow transposes + hs f32->bf16, one launch ----------
__global__ __launch_bounds__(256) void k_wtrans(const float* __restrict__ qw,
                                                const float* __restrict__ kw,
                                                const float* __restrict__ vw,
                                                const float* __restrict__ ow,
                                                const float* __restrict__ hs,
                                                u16* __restrict__ wt,
                                                u16* __restrict__ wt2,
                                                u16* __restrict__ hsb) {
  int bx = blockIdx.x;
  if (bx >= 128) {
    int g = ((bx - 128) * 56 + blockIdx.y) * 256 + threadIdx.x;  // 8-elem groups
    int row = g / 448, c8 = g % 448;
    const float4* p = (const float4*)(hs + (size_t)g * 8);
    float4 a = p[0], b = p[1];
    u16x8 r;
    r[0] = f2bf(a.x); r[1] = f2bf(a.y); r[2] = f2bf(a.z); r[3] = f2bf(a.w);
    r[4] = f2bf(b.x); r[5] = f2bf(b.y); r[6] = f2bf(b.z); r[7] = f2bf(b.w);
    int dc8 = c8 ^ (row & 7);
    *(u16x8*)(hsb + (size_t)row * E_N + dc8 * 8) = r;
    return;
  }
  __shared__ float t[64][65];
  const float* in;
  u16* out;
  int C, c0;
  if (bx < 56) {
    in = qw; out = wt; C = 3584; c0 = bx * 64;
  } else if (bx < 64) {
    in = kw; out = wt + (size_t)3584 * 3584; C = 512; c0 = (bx - 56) * 64;
  } else if (bx < 72) {
    in = vw; out = wt + (size_t)4096 * 3584; C = 512; c0 = (bx - 64) * 64;
  } else {
    in = ow; out = wt2; C = 3584; c0 = (bx - 72) * 64;
  }
  int r0 = blockIdx.y * 64;
  int lr = threadIdx.x >> 6, lc = threadIdx.x & 63;
#pragma unroll
  for (int i = 0; i < 64; i += 4)
    t[lr + i][lc] = in[(size_t)(r0 + lr + i) * C + c0 + lc];
  __syncthreads();
#pragma unroll
  for (int i = 0; i < 64; i += 4) {
    int orow = c0 + lr + i;
    int sw = (orow & 7) << 3;
    out[(size_t)orow * 3584 + r0 + (lc ^ sw)] = f2bf(t[lc][lr + i]);
  }
}

// =================== GEMM BMx256, BK=64, 8 waves, balanced 4-phase =====================
// Best-measured schedule (R7/R9/R15/R18). Counted vmcnt(ISS-2) at P3 keeps tile
// T+1 resident (FIFO-traced). EPI=1: fused QKV epilogue — Q (bias, unroped);
// K (bias + RoPE + (s&15)<<3 swizzle, final); V (bias, transposed + within-64 swizzle).
#define BARR __builtin_amdgcn_s_barrier()
#define SB0 __builtin_amdgcn_sched_barrier(0)
#define LGKM0 asm volatile("s_waitcnt lgkmcnt(0)" ::: "memory")
#define VMW0 asm volatile("s_waitcnt vmcnt(0)" ::: "memory")

template <int BM, int EPI>
__global__ __launch_bounds__(512, 2) void k_gemm(const u16* __restrict__ A,
                                                 const u16* __restrict__ Bt,
                                                 float* __restrict__ Cout,
                                                 int Nn, int nxt,
                                                 const float* __restrict__ qb,
                                                 const float* __restrict__ kb,
                                                 const float* __restrict__ vb,
                                                 const float* __restrict__ cosb,
                                                 const float* __restrict__ sinb,
                                                 u16* __restrict__ Qo,
                                                 u16* __restrict__ Ko,
                                                 u16* __restrict__ Vo) {
  constexpr int NA64 = BM / 64;                 // full 64-row A units
  constexpr bool HAS_A2 = (BM % 64) != 0;       // 32-row tail
  constexpr int NFR = BM / 32;                  // m-frags per wave
  constexpr int MHA = (NFR + 1) / 2;            // first-half frags
  constexpr int MHB = NFR - MHA;                // second-half frags
  constexpr int ISS = NA64 + (HAS_A2 ? 2 : 0) + 4;  // vmem issues per tile
  constexpr int LROWS = BM + 256;
  __shared__ __align__(16) u16 L[2 * LROWS * 64];
  const int K = 3584, NKT = 56;
  const int tid = threadIdx.x;
  const int lane = tid & 63;
  const int w = tid >> 6;
  const int lr = lane & 15, lh = lane >> 4, lh8 = lh * 8;
  const int swz = (lr & 7) << 3;
  const int wr = w >> 2, wc = w & 3;  // 2 M-waves x 4 N-waves

  // bijective XCD swizzle (m204)
  const int nwg = gridDim.x;
  const int bid = blockIdx.x;
  const int q8 = nwg >> 3, r8 = nwg & 7;
  const int xcd = bid & 7, idx = bid >> 3;
  const int lb = (xcd < r8 ? xcd * (q8 + 1) : r8 * (q8 + 1) + (xcd - r8) * q8) + idx;
  const size_t m0 = (size_t)(lb / nxt) * BM;
  const size_t n0 = (size_t)(lb % nxt) << 8;

  const u16* __restrict__ Ab = A + m0 * K;
  const u16* __restrict__ Bb = Bt + n0 * K;

  const int srow = tid >> 3, scol8 = tid & 7;
  auto stg = [&](int buf, int u, int kt) {  // 64-row units: u<NA64 A, else B
    if (kt >= NKT) return;
    const u16* src;
    int ldsrow;
    if (u < NA64) {
      src = Ab + (size_t)(u * 64 + srow) * K;
      ldsrow = u * 64 + srow;
    } else {
      src = Bb + (size_t)((u - NA64) * 64 + srow) * K;
      ldsrow = BM + (u - NA64) * 64 + srow;
    }
    gload16(src + kt * 64 + scol8 * 8, &L[buf * (LROWS * 64) + ldsrow * 64 + scol8 * 8]);
  };
  auto stgA2 = [&](int buf, int kt) {  // 32-row tail, 2 width-4 issues (all waves)
    if constexpr (HAS_A2) {
      if (kt >= NKT) return;
      int c2 = (tid & 31) * 2;
#pragma unroll
      for (int jj = 0; jj < 2; ++jj) {
        int rr = NA64 * 64 + jj * 16 + (tid >> 5);
        gload4(Ab + (size_t)rr * K + kt * 64 + c2,
               &L[buf * (LROWS * 64) + rr * 64 + c2]);
      }
    }
  };
  auto vmw = [&]() {
    if constexpr (ISS == 8) { asm volatile("s_waitcnt vmcnt(6)" ::: "memory"); }
    else if constexpr (ISS == 7) { asm volatile("s_waitcnt vmcnt(5)" ::: "memory"); }
    else { asm volatile("s_waitcnt vmcnt(4)" ::: "memory"); }
  };

  f32x4 acc[NFR][4];
#pragma unroll
  for (int i = 0; i < NFR; i++)
#pragma unroll
    for (int j = 0; j < 4; j++) acc[i][j] = f32x4{0.f, 0.f, 0.f, 0.f};

  bf16x8 afA[MHA][2], afB[MHB][2], bq[2][2];

  auto rdA = [&](auto& arr, int LB, int mbase) {
    constexpr int CNT = sizeof(arr) / sizeof(arr[0]);
#pragma unroll
    for (int mm = 0; mm < CNT; ++mm)
#pragma unroll
      for (int kk = 0; kk < 2; ++kk)
        arr[mm][kk] = *(const bf16x8*)&L[LB + (wr * (BM / 2) + (mbase + mm) * 16 + lr) * 64 +
                                         ((kk * 32 + lh8) ^ swz)];
  };
  auto rdB = [&](int LB, int qbase) {
#pragma unroll
    for (int j = 0; j < 2; ++j)
#pragma unroll
      for (int kk = 0; kk < 2; ++kk)
        bq[j][kk] = *(const bf16x8*)&L[LB + (BM + (qbase + j) * 64 + wc * 16 + lr) * 64 +
                                       ((kk * 32 + lh8) ^ swz)];
  };
  auto mm4 = [&](auto& af, int mbase, int qbase) {
    constexpr int CNT = sizeof(af) / sizeof(af[0]);
    __builtin_amdgcn_s_setprio(1);
#pragma unroll
    for (int mm = 0; mm < CNT; ++mm)
#pragma unroll
      for (int j = 0; j < 2; ++j)
#pragma unroll
        for (int kk = 0; kk < 2; ++kk)
          acc[mbase + mm][qbase + j] = __builtin_amdgcn_mfma_f32_16x16x32_bf16(
              af[mm][kk], bq[j][kk], acc[mbase + mm][qbase + j], 0, 0, 0);
    __builtin_amdgcn_s_setprio(0);
  };

  // prologue: tile0 all units; tile1 all except B2,B3; counted wait drains tile0.
#pragma unroll
  for (int u = 0; u < NA64 + 4; ++u) stg(0, u, 0);
  stgA2(0, 0);
  stg(1, NA64 + 0, 1); stg(1, NA64 + 1, 1);
#pragma unroll
  for (int u = 0; u < NA64; ++u) stg(1, u, 1);
  stgA2(1, 1);
  vmw();
  BARR;

  for (int T = 0; T < NKT; ++T) {
    const int cur = T & 1;
    const int LB = cur * (LROWS * 64);
    // P0
    rdA(afA, LB, 0);
    rdB(LB, 0);
    stg(cur ^ 1, NA64 + 2, T + 1);
    stg(cur ^ 1, NA64 + 3, T + 1);
    BARR; LGKM0;
    mm4(afA, 0, 0);
    BARR;
    // P1
    rdA(afB, LB, MHA);
    stg(cur, NA64 + 0, T + 2);
    stg(cur, NA64 + 1, T + 2);
    BARR; LGKM0;
    mm4(afB, MHA, 0);
    BARR;
    // P2
    rdB(LB, 2);
    stg(cur, 0, T + 2);
    stg(cur, 1, T + 2);
    BARR; LGKM0;
    mm4(afA, 0, 2);
    BARR;
    // P3
    if constexpr (NA64 == 3) stg(cur, 2, T + 2);
    stgA2(cur, T + 2);
    if (T + 2 < NKT) { vmw(); } else { VMW0; }
    BARR;
    mm4(afB, MHA, 2);
    BARR;
  }

  if constexpr (EPI == 0) {
    const size_t Nsz = (size_t)Nn;
#pragma unroll
    for (int m = 0; m < NFR; ++m) {
      size_t row = m0 + wr * (BM / 2) + m * 16 + lh * 4;
      if (row < 2048) {
#pragma unroll
        for (int p = 0; p < 4; ++p) {
          size_t col = n0 + p * 64 + wc * 16 + lr;
#pragma unroll
          for (int r = 0; r < 4; ++r) Cout[(row + r) * Nsz + col] = acc[m][p][r];
        }
      }
    }
  } else {
    const int ntile = (int)(n0 >> 8);  // 0..17
#pragma unroll
    for (int m = 0; m < NFR; ++m) {
      size_t row = m0 + wr * (BM / 2) + m * 16 + lh * 4;
      if (row >= 2048) continue;
      if (ntile < 14) {  // Q (bias only, unroped — attn ropes in-register)
#pragma unroll
        for (int p = 0; p < 4; ++p) {
          int col = (int)n0 + p * 64 + wc * 16 + lr;
          int hh = col >> 7, d = col & 127;
          float bias = qb[col];
#pragma unroll
          for (int r = 0; r < 4; ++r)
            Qo[((size_t)hh * S_N + row + r) * D_N + d] = f2bf(acc[m][p][r] + bias);
        }
      } else if (ntile < 16) {
        // K: bias + RoPE + swizzled write (FINAL). Pair (p=2pp, p=2pp+1) = (d0, d0+64)
        // of kvh = (ntile-14)*2 + pp; d0 = wc*16+lr in [0,64).
        int d0 = wc * 16 + lr;
#pragma unroll
        for (int pp = 0; pp < 2; ++pp) {
          int kvh = (ntile - 14) * 2 + pp;
          float blo = kb[kvh * 128 + d0];
          float bhi = kb[kvh * 128 + d0 + 64];
#pragma unroll
          for (int r = 0; r < 4; ++r) {
            int s = (int)row + r;
            float cl = cosb[s * D_N + d0], sl = sinb[s * D_N + d0];
            float ch = cosb[s * D_N + d0 + 64], sh = sinb[s * D_N + d0 + 64];
            float x0 = acc[m][2 * pp][r] + blo;
            float x1 = acc[m][2 * pp + 1][r] + bhi;
            float y0 = x0 * cl - x1 * sl;
            float y1 = x1 * ch + x0 * sh;
            int sw = (s & 15) << 3;
            u16* kp = Ko + ((size_t)kvh * S_N + s) * D_N;
            kp[d0 ^ sw] = f2bf(y0);
            kp[(d0 + 64) ^ sw] = f2bf(y1);
          }
        }
      } else {  // V -> transposed [cc][s], within-64 swizzle; 4-run contiguous in s
#pragma unroll
        for (int p = 0; p < 4; ++p) {
          int col = (int)n0 + p * 64 + wc * 16 + lr;
          int cc = col - 4096;
          float bias = vb[cc];
          int s = (int)row;
          int pos = (s & ~63) | ((s & 63) ^ ((cc & 7) << 3));
          u16x4 vv;
#pragma unroll
          for (int r = 0; r < 4; ++r) vv[r] = f2bf(acc[m][p][r] + bias);
          *(u16x4*)(Vo + (size_t)cc * S_N + pos) = vv;
        }
      }
    }
  }
}

// ---------------- flash attention, GQA, causal; Q-RoPE fused in prologue ----------------
// qt map: constant-sum pairing — under round-robin bid->CU, CU k hosts bids k and
// k+256; qt(h<16)=15-bx, qt(h>=16)=bx => per-CU step sum == 15 (balanced makespan).
__global__ __launch_bounds__(256, 2) void k_attn(const u16* __restrict__ Q,
                                                 const u16* __restrict__ Kc,
                                                 const u16* __restrict__ Vt,
                                                 const float* __restrict__ cosb,
                                                 const float* __restrict__ sinb,
                                                 u16* __restrict__ Aout) {
  __shared__ __align__(16) u16 Klds[2][64 * 128];
  __shared__ __align__(16) u16 Vlds[2][128 * 64];
  const int h = blockIdx.y;
  const int kvh = h / 7;  // H/KVH = 7
  const int qt = (blockIdx.y & 16) ? (blockIdx.x & 15) : ((15 - blockIdx.x) & 15);
  const int q0 = qt * 128;
  const int tid = threadIdx.x, w = tid >> 6, lane = tid & 63;
  const int l31 = lane & 31, hi = lane >> 5;
  const int hi8 = hi * 8;
  const int swK = (l31 & 15) << 3;  // K-read swizzle
  const int swV = (l31 & 7) << 3;   // V-read swizzle
  const int qloc = w * 32 + l31;
  const int qrow = q0 + qloc;

  // Q fragments with in-register RoPE: frag f (d<64) pairs with f+4 (d+64).
  bf16x8 qf[8];
  {
    const u16* qp = Q + ((size_t)h * S_N + qrow) * D_N + hi8;
    const float* cb = cosb + (size_t)qrow * D_N + hi8;
    const float* sb = sinb + (size_t)qrow * D_N + hi8;
#pragma unroll
    for (int f = 0; f < 4; ++f) {
      u16x8 ulo = __builtin_bit_cast(u16x8, *(const bf16x8*)(qp + f * 16));
      u16x8 uhi = __builtin_bit_cast(u16x8, *(const bf16x8*)(qp + (f + 4) * 16));
      u16x8 olo, ohi;
#pragma unroll
      for (int e = 0; e < 8; ++e) {
        float xl = bf2f(ulo[e]), xh = bf2f(uhi[e]);
        float cl = cb[f * 16 + e], sl = sb[f * 16 + e];
        float ch = cb[(f + 4) * 16 + e], sh = sb[(f + 4) * 16 + e];
        olo[e] = f2bf(xl * cl - xh * sl);
        ohi[e] = f2bf(xh * ch + xl * sh);
      }
      qf[f] = __builtin_bit_cast(bf16x8, olo);
      qf[f + 4] = __builtin_bit_cast(bf16x8, ohi);
    }
  }

  f32x16 o[4];
#pragma unroll
  for (int i = 0; i < 4; i++)
#pragma unroll
    for (int r = 0; r < 16; r++) o[i][r] = 0.f;

  float m2 = -3.0e38f;
  float lsum = 0.f;
  const float msc = 0.12751743f;  // 1/sqrt(128) * log2(e)

  auto stageKV = [&](int buf, int t) {
    const u16* ks = Kc + ((size_t)kvh * S_N + t * 64) * D_N;
#pragma unroll
    for (int j = 0; j < 4; ++j)
      gload16(ks + (j * 256 + tid) * 8, &Klds[buf][(j * 256 + tid) * 8]);
    const u16* vs = Vt + (size_t)kvh * D_N * S_N + t * 64;
#pragma unroll
    for (int j = 0; j < 4; ++j) {
      int idx = j * 256 + tid;
      int dd = idx >> 3, cw = idx & 7;
      gload16(vs + (size_t)dd * S_N + cw * 8, &Vlds[buf][idx * 8]);
    }
  };

  const int nt = 2 * qt + 2;
  stageKV(0, 0);
  for (int t = 0; t < nt; ++t) {
    const int cur = t & 1;
    if (t + 1 < nt) {
      stageKV(cur ^ 1, t + 1);
      asm volatile("s_waitcnt vmcnt(8)" ::: "memory");  // tile t resident (FIFO)
    } else {
      asm volatile("s_waitcnt vmcnt(0)" ::: "memory");
    }
    SB0; BARR; SB0;
    f32x16 sacc[2];
#pragma unroll
    for (int i = 0; i < 2; i++)
#pragma unroll
      for (int r = 0; r < 16; r++) sacc[i][r] = 0.f;
    __builtin_amdgcn_s_setprio(1);
#pragma unroll
    for (int dstep = 0; dstep < 8; ++dstep)
#pragma unroll
      for (int ksub = 0; ksub < 2; ++ksub) {
        bf16x8 ka =
            *(const bf16x8*)&Klds[cur][(ksub * 32 + l31) * D_N + ((dstep * 16 + hi8) ^ swK)];
        sacc[ksub] = __builtin_amdgcn_mfma_f32_32x32x16_bf16(ka, qf[dstep], sacc[ksub], 0, 0, 0);
      }
    __builtin_amdgcn_s_setprio(0);
    if (t >= nt - 2) {
#pragma unroll
      for (int ksub = 0; ksub < 2; ++ksub)
#pragma unroll
        for (int r = 0; r < 16; ++r) {
          int kvg = t * 64 + ksub * 32 + (r & 3) + 8 * (r >> 2) + 4 * hi;
          sacc[ksub][r] = (kvg <= qrow) ? sacc[ksub][r] * msc : -3.0e38f;
        }
    } else {
#pragma unroll
      for (int ksub = 0; ksub < 2; ++ksub)
#pragma unroll
        for (int r = 0; r < 16; ++r) sacc[ksub][r] *= msc;
    }
    float tmax = fmaxf(vmax16(sacc[0]), vmax16(sacc[1]));
    tmax = fmaxf(tmax, __shfl_xor(tmax, 32));  // cross-half max
    if (__any(tmax > m2 + 8.0f)) {
      float m2new = fmaxf(m2, tmax);
      float scl = __builtin_amdgcn_exp2f(m2 - m2new);
#pragma unroll
      for (int i = 0; i < 4; i++)
#pragma unroll
        for (int r = 0; r < 16; r++) o[i][r] *= scl;
      lsum *= scl;
      m2 = m2new;
    }
#pragma unroll
    for (int ksub = 0; ksub < 2; ++ksub) {
#pragma unroll
      for (int r = 0; r < 16; ++r)
        sacc[ksub][r] = __builtin_amdgcn_exp2f(sacc[ksub][r] - m2);
      lsum += vsum16(sacc[ksub]);
    }
    __builtin_amdgcn_s_setprio(1);
#pragma unroll
    for (int ksub = 0; ksub < 2; ++ksub) {
      u32 pw[8];
#pragma unroll
      for (int i = 0; i < 8; ++i) pw[i] = cvt_pk_bf16(sacc[ksub][2 * i], sacc[ksub][2 * i + 1]);
      pl32swap(pw[0], pw[2]);
      pl32swap(pw[1], pw[3]);
      pl32swap(pw[4], pw[6]);
      pl32swap(pw[5], pw[7]);
#pragma unroll
      for (int j = 0; j < 2; ++j) {
        u32x4 fw = {pw[j * 4 + 0], pw[j * 4 + 1], pw[j * 4 + 2], pw[j * 4 + 3]};
        bf16x8 pb = __builtin_bit_cast(bf16x8, fw);
#pragma unroll
        for (int dsub = 0; dsub < 4; ++dsub) {
          bf16x8 va = *(const bf16x8*)&Vlds[cur][(dsub * 32 + l31) * 64 +
                                                 ((ksub * 32 + j * 16 + hi8) ^ swV)];
          o[dsub] = __builtin_amdgcn_mfma_f32_32x32x16_bf16(va, pb, o[dsub], 0, 0, 0);
        }
      }
    }
    __builtin_amdgcn_s_setprio(0);
    SB0; BARR; SB0;
  }
  float lt = lsum + __shfl_xor(lsum, 32);
  float ri = 1.0f / lt;
  u16* op = Aout + (size_t)qrow * E_N + h * D_N;
  const int sw2 = (qrow & 7) << 3;  // GEMM-A pre-swizzle
#pragma unroll
  for (int dsub = 0; dsub < 4; ++dsub)
#pragma unroll
    for (int g = 0; g < 4; ++g) {
      int dbase = dsub * 32 + 8 * g + 4 * hi;
      u32x2 wv;
      wv[0] = (u32)f2bf(o[dsub][g * 4 + 0] * ri) | ((u32)f2bf(o[dsub][g * 4 + 1] * ri) << 16);
      wv[1] = (u32)f2bf(o[dsub][g * 4 + 2] * ri) | ((u32)f2bf(o[dsub][g * 4 + 3] * ri) << 16);
      *(u32x2*)(op + (dbase ^ sw2)) = wv;
    }
}

extern "C" void kernel_launch(void* const* d_in, const int* in_sizes, int n_in,
                              void* d_out, int out_size, void* d_ws, size_t ws_size,
                              hipStream_t stream) {
  const float* hs   = (const float*)d_in[0];
  const float* cosb = (const float*)d_in[1];
  const float* sinb = (const float*)d_in[2];
  // d_in[3] = attn_mask (causal tril — applied analytically)
  const float* qw = (const float*)d_in[4];
  const float* qb = (const float*)d_in[5];
  const float* kw = (const float*)d_in[6];
  const float* kb = (const float*)d_in[7];
  const float* vw = (const float*)d_in[8];
  const float* vb = (const float*)d_in[9];
  const float* ow = (const float*)d_in[10];
  float* outp = (float*)d_out;

  char* ws = (char*)d_ws;
  u16* hsb    = (u16*)(ws);                       // 2048x3584 bf16 (swz)           14.7MB
  u16* wt     = (u16*)(ws + 14680064);            // 4608x3584 bf16 (swz)             33MB
  u16* wt2    = (u16*)(ws + 47710208);            // 3584x3584 ow^T bf16 (swz)      25.7MB
  u16* attn_o = (u16*)(ws + 73400320);            // 2048x3584 bf16 (swz)           14.7MB
  u16* Qb     = (u16*)(ws + 88080384);            // [28][2048][128] (unroped)      14.7MB
  u16* Kb     = (u16*)(ws + 102760448);           // [4][2048][128] (roped+swz)       2MB
  u16* Vtb    = (u16*)(ws + 104857600);           // [512][2048] (swz within-64)      2MB

  // 1. merged prepass: weight transposes + hs->bf16 (one launch)
  k_wtrans<<<dim3(192, 56), dim3(256), 0, stream>>>(qw, kw, vw, ow, hs, wt, wt2, hsb);
  // 2. QKV GEMM, BM=160 (234 blocks, 91% fill), fused bias+RoPE(K)+layout epilogue
  k_gemm<160, 1><<<dim3(234), dim3(512), 0, stream>>>(hsb, wt, nullptr, 4608, 18,
                                                      qb, kb, vb, cosb, sinb, Qb, Kb, Vtb);
  // 3. attention -> attn_o (bf16, GEMM-swizzled); Q roped in-register
  k_attn<<<dim3(16, 28), dim3(256), 0, stream>>>(Qb, Kb, Vtb, cosb, sinb, attn_o);
  // 4. output projection, BM=128 (224 blocks)
  k_gemm<128, 0><<<dim3(224), dim3(512), 0, stream>>>(attn_o, wt2, outp, 3584, 14,
                                                      nullptr, nullptr, nullptr,
                                                      nullptr, nullptr,
                                                      nullptr, nullptr, nullptr);
}